// Round 2
// baseline (894.703 us; speedup 1.0000x reference)
//
#include <hip/hip_runtime.h>
#include <stdint.h>

// ---- problem constants ----
#define D_MODEL  2048
#define N_INTER  1408
#define SH_INTER 2816
#define T_TOK    2048
#define NSLOT    (T_TOK * 4)

typedef __attribute__((ext_vector_type(8))) short bf16x8;
typedef __attribute__((ext_vector_type(4))) float f32x4;

__device__ __forceinline__ unsigned short f2bf(float f){
  unsigned int b = __builtin_bit_cast(unsigned int, f);
  b = (b + 0x7FFFu + ((b >> 16) & 1u)) >> 16;   // RNE, finite inputs
  return (unsigned short)b;
}
__device__ __forceinline__ float bf2f(unsigned short h){
  unsigned int b = ((unsigned int)h) << 16;
  return __builtin_bit_cast(float, b);
}

// async global->LDS, 16B per lane; LDS dest = wave-uniform base + lane*16
#define GLOAD16(gp, lp) __builtin_amdgcn_global_load_lds( \
    (const __attribute__((address_space(1))) unsigned int*)(gp), \
    (__attribute__((address_space(3))) unsigned int*)(lp), 16, 0, 0)

// ---------------- fp32 -> bf16 convert (x only) ----------------
__global__ void cvt_bf16_kernel(const float* __restrict__ x,
                                unsigned short* __restrict__ o, int n4){
  const int i = blockIdx.x * blockDim.x + threadIdx.x;
  if (i >= n4) return;
  const float4 v = ((const float4*)x)[i];
  ushort4 u; u.x = f2bf(v.x); u.y = f2bf(v.y); u.z = f2bf(v.z); u.w = f2bf(v.w);
  ((ushort4*)o)[i] = u;
}

// ---------------- gate: softmax + group-limited top-k ----------------
__global__ void gate_kernel(const float* __restrict__ x, const float* __restrict__ Wg,
                            int* __restrict__ cnt, int* __restrict__ list,
                            float* __restrict__ wslot){
  const int t = blockIdx.x;
  const int l = threadIdx.x;
  const int e = l & 15, q = l >> 4;
  const float* xr = x + (size_t)t * D_MODEL + q * 512;
  const float* wr = Wg + (size_t)e * D_MODEL + q * 512;
  float p = 0.f;
  #pragma unroll 4
  for (int i = 0; i < 512; i += 4){
    float4 xv = *(const float4*)(xr + i);
    float4 wv = *(const float4*)(wr + i);
    p += xv.x*wv.x + xv.y*wv.y + xv.z*wv.z + xv.w*wv.w;
  }
  p += __shfl_xor(p, 16);
  p += __shfl_xor(p, 32);
  float mx = p;
  for (int d = 1; d < 16; d <<= 1) mx = fmaxf(mx, __shfl_xor(mx, d));
  float ex = __expf(p - mx);
  float sum = ex;
  for (int d = 1; d < 16; d <<= 1) sum += __shfl_xor(sum, d);
  const float sc = ex / sum;
  float gm = fmaxf(sc, __shfl_xor(sc, 1));
  gm = fmaxf(gm, __shfl_xor(gm, 2));
  const float g0 = __shfl(gm, 0), g1 = __shfl(gm, 4),
              g2 = __shfl(gm, 8), g3 = __shfl(gm, 12);
  const int grp = e >> 2;
  const float gs[4] = {g0, g1, g2, g3};
  int grank = 0;
  #pragma unroll
  for (int j = 0; j < 4; ++j)
    if (gs[j] > gm || (gs[j] == gm && j < grp)) grank++;
  const float msc = (grank < 2) ? sc : -INFINITY;
  int erank = 0;
  #pragma unroll
  for (int j = 0; j < 16; ++j){
    const float oj = __shfl(msc, j);
    if (oj > msc || (oj == msc && j < e)) erank++;
  }
  if (q == 0 && erank < 4 && msc > -INFINITY){
    const int pos = atomicAdd(&cnt[e], 1);
    const int slot = (t << 2) | erank;
    list[e * T_TOK + pos] = slot;
    wslot[slot] = sc;            // ROUTE_SCALE = 1
  }
}

// ---------------- pipelined bf16-MFMA GEMM, BM=128 BN=64 BK=32 ----------------
// MODE 0: linear A, bf16 out (shared G / U)
// MODE 1: linear A, fp32 out (shared down -> d_out)
// MODE 2: gathered A by token (entry>>2), bf16 out at slot (routed G / U)
// MODE 3: gathered A by slot (entry),     bf16 out at slot (routed down)
// A bf16 [*][K]; B fp32 [E?][N][K] converted to bf16 during staging.
template<int MODE>
__global__ __launch_bounds__(256, 2)
void gemm2_kernel(const unsigned short* __restrict__ A,
                  const float* __restrict__ B,
                  void* __restrict__ OutP,
                  const int* __restrict__ list,
                  const int* __restrict__ cnt,
                  int N, int K, int MT, int NT)
{
  constexpr bool GATHER = (MODE >= 2);
  __shared__ unsigned short As[2 * 128 * 32];   // A double buffer, linear (gload_lds)
  __shared__ unsigned short Bs[64 * 32];        // B single buffer (reg-staged)

  // bijective XCD-chunked swizzle (grid % 8 == 0 for all launches)
  const int per = gridDim.x >> 3;
  const int gsw = (blockIdx.x & 7) * per + (blockIdx.x >> 3);
  const int mt   = gsw % MT;
  const int rest = gsw / MT;
  const int nt = GATHER ? (rest % NT) : rest;
  const int e  = GATHER ? (rest / NT) : 0;

  const int cntE = GATHER ? cnt[e] : (MT * 128);
  if (mt * 128 >= cntE) return;

  const int tid = threadIdx.x, wid = tid >> 6, lane = tid & 63;

  // ---- A staging (global_load_lds, pre-swizzled source) ----
  // wave w stages rows [32w,32w+32) as 2 chunks of 16 rows; lane -> row +=(l>>2), phys slot l&3
  const int rt0 = 32 * wid + (lane >> 2), rt1 = rt0 + 16;
  int ar0, ar1;
  if constexpr (GATHER){
    const int lim = cntE - 1;
    int p0 = mt * 128 + rt0; p0 = p0 < lim ? p0 : lim;
    int p1 = mt * 128 + rt1; p1 = p1 < lim ? p1 : lim;
    const int e0 = list[e * T_TOK + p0], e1 = list[e * T_TOK + p1];
    ar0 = (MODE == 2) ? (e0 >> 2) : e0;
    ar1 = (MODE == 2) ? (e1 >> 2) : e1;
  } else { ar0 = mt * 128 + rt0; ar1 = mt * 128 + rt1; }
  // source logical 16B-slot = phys ^ ((row>>1)&3)  (involution; read applies same XOR)
  const unsigned short* pa0 = A + (size_t)ar0 * K + (((lane & 3) ^ ((rt0 >> 1) & 3)) << 3);
  const unsigned short* pa1 = A + (size_t)ar1 * K + (((lane & 3) ^ ((rt1 >> 1) & 3)) << 3);
  unsigned short* const asBase = &As[0];
  const int aW0 = (32 * wid) * 32, aW1 = (32 * wid + 16) * 32;   // shorts
  const int bufStride = 128 * 32;

  // ---- B staging (reg-staged fp32 -> bf16, swizzled ds_write) ----
  const int brow = tid >> 2, bsl = tid & 3;
  const float* pb = B + (GATHER ? (size_t)e * N * K : 0)
                  + (size_t)(nt * 64 + brow) * K
                  + (((bsl ^ ((brow >> 1) & 3))) << 3);
  unsigned short* const bsDst = &Bs[brow * 32 + (bsl << 3)];

  // ---- fragment read offsets ----
  const int wr = wid >> 1, wc = wid & 1, lr = lane & 15, lq = lane >> 4;
  const int fx = ((lq ^ ((lr >> 1) & 3)) << 3);
  int aoff[4], boff[2];
  #pragma unroll
  for (int m = 0; m < 4; ++m) aoff[m] = (wr * 64 + m * 16 + lr) * 32 + fx;
  #pragma unroll
  for (int n = 0; n < 2; ++n) boff[n] = (wc * 32 + n * 16 + lr) * 32 + fx;

  f32x4 acc[4][2];
  const f32x4 zero = {0.f, 0.f, 0.f, 0.f};
  #pragma unroll
  for (int m = 0; m < 4; ++m)
    #pragma unroll
    for (int n = 0; n < 2; ++n) acc[m][n] = zero;

  const int KT = K >> 5;
  // prologue: stage kt=0
  GLOAD16(pa0, asBase + aW0);
  GLOAD16(pa1, asBase + aW1);
  float4 bp0 = *(const float4*)pb;
  float4 bp1 = *(const float4*)(pb + 4);
  pa0 += 32; pa1 += 32; pb += 32;
  int cur = 0;

  for (int kt = 0; kt < KT; ++kt){
    __syncthreads();                     // drains vmem: A[cur] + bp landed; prev LDS reads done
    bf16x8 ub;
    ub[0] = (short)f2bf(bp0.x); ub[1] = (short)f2bf(bp0.y);
    ub[2] = (short)f2bf(bp0.z); ub[3] = (short)f2bf(bp0.w);
    ub[4] = (short)f2bf(bp1.x); ub[5] = (short)f2bf(bp1.y);
    ub[6] = (short)f2bf(bp1.z); ub[7] = (short)f2bf(bp1.w);
    *(bf16x8*)bsDst = ub;
    __syncthreads();                     // Bs + As[cur] visible to all
    if (kt + 1 < KT){                    // prefetch AFTER barrier: flies through MFMA phase
      const int nxt = cur ^ 1;
      GLOAD16(pa0, asBase + nxt * bufStride + aW0);
      GLOAD16(pa1, asBase + nxt * bufStride + aW1);
      bp0 = *(const float4*)pb;
      bp1 = *(const float4*)(pb + 4);
      pa0 += 32; pa1 += 32; pb += 32;
    }
    const unsigned short* aCur = asBase + cur * bufStride;
    bf16x8 af0 = *(const bf16x8*)(aCur + aoff[0]);
    bf16x8 af1 = *(const bf16x8*)(aCur + aoff[1]);
    bf16x8 af2 = *(const bf16x8*)(aCur + aoff[2]);
    bf16x8 af3 = *(const bf16x8*)(aCur + aoff[3]);
    bf16x8 bf0 = *(const bf16x8*)(&Bs[0] + boff[0]);
    bf16x8 bf1 = *(const bf16x8*)(&Bs[0] + boff[1]);
    acc[0][0] = __builtin_amdgcn_mfma_f32_16x16x32_bf16(af0, bf0, acc[0][0], 0, 0, 0);
    acc[1][0] = __builtin_amdgcn_mfma_f32_16x16x32_bf16(af1, bf0, acc[1][0], 0, 0, 0);
    acc[2][0] = __builtin_amdgcn_mfma_f32_16x16x32_bf16(af2, bf0, acc[2][0], 0, 0, 0);
    acc[3][0] = __builtin_amdgcn_mfma_f32_16x16x32_bf16(af3, bf0, acc[3][0], 0, 0, 0);
    acc[0][1] = __builtin_amdgcn_mfma_f32_16x16x32_bf16(af0, bf1, acc[0][1], 0, 0, 0);
    acc[1][1] = __builtin_amdgcn_mfma_f32_16x16x32_bf16(af1, bf1, acc[1][1], 0, 0, 0);
    acc[2][1] = __builtin_amdgcn_mfma_f32_16x16x32_bf16(af2, bf1, acc[2][1], 0, 0, 0);
    acc[3][1] = __builtin_amdgcn_mfma_f32_16x16x32_bf16(af3, bf1, acc[3][1], 0, 0, 0);
    cur ^= 1;
  }

  // ---- epilogue: C/D col = lane&15, row = (lane>>4)*4 + reg ----
  const int colBase = nt * 64 + wc * 32;
  if constexpr (MODE == 1){
    float* O = (float*)OutP;
    #pragma unroll
    for (int m = 0; m < 4; ++m){
      #pragma unroll
      for (int r = 0; r < 4; ++r){
        const int grow = mt * 128 + wr * 64 + m * 16 + lq * 4 + r;
        float* op = O + (size_t)grow * N + colBase;
        op[lr]      = acc[m][0][r];
        op[16 + lr] = acc[m][1][r];
      }
    }
  } else {
    unsigned short* O = (unsigned short*)OutP;
    #pragma unroll
    for (int m = 0; m < 4; ++m){
      #pragma unroll
      for (int r = 0; r < 4; ++r){
        const int grow = mt * 128 + wr * 64 + m * 16 + lq * 4 + r;
        int orow;
        if constexpr (GATHER){
          if (grow >= cntE) continue;
          orow = list[e * T_TOK + grow];        // slot
        } else orow = grow;
        unsigned short* op = O + (size_t)orow * N + colBase;
        op[lr]      = f2bf(acc[m][0][r]);
        op[16 + lr] = f2bf(acc[m][1][r]);
      }
    }
  }
}

// ---------------- SwiGLU: H = silu(G) * U (bf16) ----------------
__global__ void swiglu_kernel(const unsigned short* __restrict__ G,
                              const unsigned short* __restrict__ U,
                              unsigned short* __restrict__ H, int n8){
  const int i = blockIdx.x * blockDim.x + threadIdx.x;
  if (i >= n8) return;
  const bf16x8 g = ((const bf16x8*)G)[i];
  const bf16x8 u = ((const bf16x8*)U)[i];
  bf16x8 h;
  #pragma unroll
  for (int j = 0; j < 8; ++j){
    const float gv = bf2f((unsigned short)g[j]);
    const float uv = bf2f((unsigned short)u[j]);
    h[j] = (short)f2bf(gv / (1.f + __expf(-gv)) * uv);
  }
  ((bf16x8*)H)[i] = h;
}

// ---------------- combine: out[t] += sum_k wslot[4t+k] * H2[4t+k] ----------------
__global__ void combine_kernel(const unsigned short* __restrict__ H2,
                               const float* __restrict__ wslot,
                               float* __restrict__ out){
  const int t = blockIdx.x;
  const int c = threadIdx.x * 8;
  float w[4];
  #pragma unroll
  for (int k = 0; k < 4; ++k) w[k] = wslot[t * 4 + k];
  float* o = out + (size_t)t * D_MODEL + c;
  float a[8];
  #pragma unroll
  for (int j = 0; j < 8; ++j) a[j] = o[j];
  #pragma unroll
  for (int k = 0; k < 4; ++k){
    const bf16x8 hv = *(const bf16x8*)(H2 + (size_t)(t * 4 + k) * D_MODEL + c);
    #pragma unroll
    for (int j = 0; j < 8; ++j) a[j] += w[k] * bf2f((unsigned short)hv[j]);
  }
  #pragma unroll
  for (int j = 0; j < 8; ++j) o[j] = a[j];
}

extern "C" void kernel_launch(void* const* d_in, const int* in_sizes, int n_in,
                              void* d_out, int out_size, void* d_ws, size_t ws_size,
                              hipStream_t stream)
{
  const float* x   = (const float*)d_in[0];
  const float* Wg  = (const float*)d_in[1];
  const float* W1  = (const float*)d_in[2];
  const float* W3  = (const float*)d_in[3];
  const float* W2  = (const float*)d_in[4];
  const float* Ws1 = (const float*)d_in[5];
  const float* Ws3 = (const float*)d_in[6];
  const float* Ws2 = (const float*)d_in[7];
  float* out = (float*)d_out;

  char* ws = (char*)d_ws;
  int*            cnt   = (int*)(ws);                       // 64 B
  int*            list  = (int*)(ws + 4096);                // 128 KiB
  float*          wslot = (float*)(ws + 4096 + 131072);     // 32 KiB
  unsigned short* xbf = (unsigned short*)(ws + ((size_t)1  << 20));  // 8.4 MB
  unsigned short* Gs  = (unsigned short*)(ws + ((size_t)10 << 20));  // 11.6 MB
  unsigned short* Us  = (unsigned short*)(ws + ((size_t)22 << 20));  // 11.6 MB
  unsigned short* Hs  = (unsigned short*)(ws + ((size_t)34 << 20));  // 11.6 MB
  unsigned short* Gr  = (unsigned short*)(ws + ((size_t)46 << 20));  // 23.1 MB
  unsigned short* Ur  = (unsigned short*)(ws + ((size_t)70 << 20));  // 23.1 MB
  unsigned short* Hr  = (unsigned short*)(ws + ((size_t)94 << 20));  // 23.1 MB
  unsigned short* H2  = (unsigned short*)(ws + ((size_t)118 << 20)); // 33.6 MB

  hipMemsetAsync(cnt, 0, 4096, stream);
  cvt_bf16_kernel<<<(T_TOK * D_MODEL / 4) / 256, 256, 0, stream>>>(x, xbf, T_TOK * D_MODEL / 4);
  gate_kernel<<<T_TOK, 64, 0, stream>>>(x, Wg, cnt, list, wslot);

  // ---- shared expert ----
  gemm2_kernel<0><<<16 * 44, 256, 0, stream>>>(xbf, Ws1, Gs, nullptr, nullptr,
                                               SH_INTER, D_MODEL, 16, 44);
  gemm2_kernel<0><<<16 * 44, 256, 0, stream>>>(xbf, Ws3, Us, nullptr, nullptr,
                                               SH_INTER, D_MODEL, 16, 44);
  swiglu_kernel<<<(T_TOK * SH_INTER / 8) / 256, 256, 0, stream>>>(Gs, Us, Hs,
                                               T_TOK * SH_INTER / 8);
  gemm2_kernel<1><<<16 * 32, 256, 0, stream>>>(Hs, Ws2, out, nullptr, nullptr,
                                               D_MODEL, SH_INTER, 16, 32);

  // ---- routed experts ----
  gemm2_kernel<2><<<16 * 22 * 16, 256, 0, stream>>>(xbf, W1, Gr, list, cnt,
                                                    N_INTER, D_MODEL, 16, 22);
  gemm2_kernel<2><<<16 * 22 * 16, 256, 0, stream>>>(xbf, W3, Ur, list, cnt,
                                                    N_INTER, D_MODEL, 16, 22);
  swiglu_kernel<<<(NSLOT * N_INTER / 8) / 256, 256, 0, stream>>>(Gr, Ur, Hr,
                                                    NSLOT * N_INTER / 8);
  gemm2_kernel<3><<<16 * 32 * 16, 256, 0, stream>>>(Hr, W2, H2, list, cnt,
                                                    D_MODEL, N_INTER, 16, 32);
  combine_kernel<<<T_TOK, 256, 0, stream>>>(H2, wslot, out);
}

// Round 3
// 830.574 us; speedup vs baseline: 1.0772x; 1.0772x over previous
//
#include <hip/hip_runtime.h>
#include <stdint.h>

// ---- problem constants ----
#define D_MODEL  2048
#define N_INTER  1408
#define SH_INTER 2816
#define T_TOK    2048
#define NSLOT    (T_TOK * 4)

typedef __attribute__((ext_vector_type(8))) short bf16x8;
typedef __attribute__((ext_vector_type(4))) float f32x4;

__device__ __forceinline__ unsigned short f2bf(float f){
  unsigned int b = __builtin_bit_cast(unsigned int, f);
  b = (b + 0x7FFFu + ((b >> 16) & 1u)) >> 16;   // RNE, finite inputs
  return (unsigned short)b;
}
__device__ __forceinline__ float bf2f(unsigned short h){
  unsigned int b = ((unsigned int)h) << 16;
  return __builtin_bit_cast(float, b);
}

// async global->LDS, 16B per lane; LDS dest = wave-uniform base + lane*16
#define GLOAD16(gp, lp) __builtin_amdgcn_global_load_lds( \
    (const __attribute__((address_space(1))) unsigned int*)(gp), \
    (__attribute__((address_space(3))) unsigned int*)(lp), 16, 0, 0)

// ---------------- fp32 -> bf16 convert (x only) ----------------
__global__ void cvt_bf16_kernel(const float* __restrict__ x,
                                unsigned short* __restrict__ o, int n4){
  const int i = blockIdx.x * blockDim.x + threadIdx.x;
  if (i >= n4) return;
  const float4 v = ((const float4*)x)[i];
  ushort4 u; u.x = f2bf(v.x); u.y = f2bf(v.y); u.z = f2bf(v.z); u.w = f2bf(v.w);
  ((ushort4*)o)[i] = u;
}

// ---------------- gate: softmax + group-limited top-k ----------------
__global__ void gate_kernel(const float* __restrict__ x, const float* __restrict__ Wg,
                            int* __restrict__ cnt, int* __restrict__ list,
                            float* __restrict__ wslot){
  const int t = blockIdx.x;
  const int l = threadIdx.x;
  const int e = l & 15, q = l >> 4;
  const float* xr = x + (size_t)t * D_MODEL + q * 512;
  const float* wr = Wg + (size_t)e * D_MODEL + q * 512;
  float p = 0.f;
  #pragma unroll 4
  for (int i = 0; i < 512; i += 4){
    float4 xv = *(const float4*)(xr + i);
    float4 wv = *(const float4*)(wr + i);
    p += xv.x*wv.x + xv.y*wv.y + xv.z*wv.z + xv.w*wv.w;
  }
  p += __shfl_xor(p, 16);
  p += __shfl_xor(p, 32);
  float mx = p;
  for (int d = 1; d < 16; d <<= 1) mx = fmaxf(mx, __shfl_xor(mx, d));
  float ex = __expf(p - mx);
  float sum = ex;
  for (int d = 1; d < 16; d <<= 1) sum += __shfl_xor(sum, d);
  const float sc = ex / sum;
  float gm = fmaxf(sc, __shfl_xor(sc, 1));
  gm = fmaxf(gm, __shfl_xor(gm, 2));
  const float g0 = __shfl(gm, 0), g1 = __shfl(gm, 4),
              g2 = __shfl(gm, 8), g3 = __shfl(gm, 12);
  const int grp = e >> 2;
  const float gs[4] = {g0, g1, g2, g3};
  int grank = 0;
  #pragma unroll
  for (int j = 0; j < 4; ++j)
    if (gs[j] > gm || (gs[j] == gm && j < grp)) grank++;
  const float msc = (grank < 2) ? sc : -INFINITY;
  int erank = 0;
  #pragma unroll
  for (int j = 0; j < 16; ++j){
    const float oj = __shfl(msc, j);
    if (oj > msc || (oj == msc && j < e)) erank++;
  }
  if (q == 0 && erank < 4 && msc > -INFINITY){
    const int pos = atomicAdd(&cnt[e], 1);
    const int slot = (t << 2) | erank;
    list[e * T_TOK + pos] = slot;
    wslot[slot] = sc;            // ROUTE_SCALE = 1
  }
}

// ------- fused bf16-MFMA GEMM, BM=128 BN=128 BK=32, 4 waves (2x2 of 64x64) -------
// MODE 0: linear A, dual B (SwiGLU), bf16 out            (shared gate+up -> Hs)
// MODE 1: linear A, single B, fp32 out                   (shared down -> d_out)
// MODE 2: gathered A by token (entry>>2), dual B, bf16 out at slot (routed G+U -> Hr)
// MODE 3: gathered A by slot (entry), single B, bf16 out at slot   (routed down -> H2)
// A bf16 [*][K]; B fp32 [E?][N][K] converted to bf16 in registers during staging.
template<int MODE>
__global__ __launch_bounds__(256, 2)
void gemm3_kernel(const unsigned short* __restrict__ A,
                  const float* __restrict__ B1,
                  const float* __restrict__ B3,
                  void* __restrict__ OutP,
                  const int* __restrict__ list,
                  const int* __restrict__ cnt,
                  int N, int K, int MT, int NT)
{
  constexpr bool DUAL   = (MODE == 0 || MODE == 2);
  constexpr bool GATHER = (MODE >= 2);

  __shared__ unsigned short As [2 * 128 * 32];   // A double buffer (gload_lds, pre-swz src)
  __shared__ unsigned short Bs1[128 * 32];       // B single buffer (reg-staged, swz write)
  __shared__ unsigned short Bs3[DUAL ? 128 * 32 : 8];

  // bijective XCD-chunked swizzle (all grids % 8 == 0)
  const int per = gridDim.x >> 3;
  const int gsw = (blockIdx.x & 7) * per + (blockIdx.x >> 3);
  const int mt   = gsw % MT;
  const int rest = gsw / MT;
  const int nt = GATHER ? (rest % NT) : rest;
  const int e  = GATHER ? (rest / NT) : 0;

  const int cntE = GATHER ? cnt[e] : (MT * 128);
  if (mt * 128 >= cntE) return;

  const int tid = threadIdx.x, wid = tid >> 6, lane = tid & 63;

  // ---- A staging (global_load_lds dbuf; source pre-swizzled so reads can XOR) ----
  // wave w stages rows [32w,32w+32): 2 insts x 16 rows; lane -> row += lane>>2, slot lane&3
  const int rt0 = 32 * wid + (lane >> 2), rt1 = rt0 + 16;
  int ar0, ar1;
  if constexpr (GATHER){
    const int lim = cntE - 1;
    int p0 = mt * 128 + rt0; p0 = p0 < lim ? p0 : lim;
    int p1 = mt * 128 + rt1; p1 = p1 < lim ? p1 : lim;
    const int e0 = list[e * T_TOK + p0], e1 = list[e * T_TOK + p1];
    ar0 = (MODE == 2) ? (e0 >> 2) : e0;
    ar1 = (MODE == 2) ? (e1 >> 2) : e1;
  } else { ar0 = mt * 128 + rt0; ar1 = mt * 128 + rt1; }
  const unsigned short* pa0 = A + (size_t)ar0 * K + (((lane & 3) ^ ((rt0 >> 1) & 3)) << 3);
  const unsigned short* pa1 = A + (size_t)ar1 * K + (((lane & 3) ^ ((rt1 >> 1) & 3)) << 3);
  unsigned short* const asBase = &As[0];
  const int aW0 = (32 * wid) * 32, aW1 = (32 * wid + 16) * 32;   // shorts
  const int bufStride = 128 * 32;

  // ---- B staging: thread t -> row r=t>>1, half s=t&1 (16 floats); swizzled ds_write ----
  const int br = tid >> 1, bsh = tid & 1;
  const size_t Boff = GATHER ? (size_t)e * N * K : 0;
  const float* pb1 = B1 + Boff + (size_t)(nt * 128 + br) * K + bsh * 16;
  const float* pb3 = nullptr;
  if constexpr (DUAL) pb3 = B3 + Boff + (size_t)(nt * 128 + br) * K + bsh * 16;
  const int bxr = (br >> 1) & 3;
  const int bo0 = br * 32 + (((2 * bsh)     ^ bxr) << 3);   // shorts
  const int bo1 = br * 32 + (((2 * bsh + 1) ^ bxr) << 3);

  // ---- fragment read offsets (logical slot lq XOR'd with row bits) ----
  const int wr = wid >> 1, wc = wid & 1, lr = lane & 15, lq = lane >> 4;
  const int fx = ((lq ^ ((lr >> 1) & 3)) << 3);
  int aoff[4], boff[4];
  #pragma unroll
  for (int m = 0; m < 4; ++m) aoff[m] = (wr * 64 + m * 16 + lr) * 32 + fx;
  #pragma unroll
  for (int n = 0; n < 4; ++n) boff[n] = (wc * 64 + n * 16 + lr) * 32 + fx;

  f32x4 acc1[4][4];
  f32x4 acc3[DUAL ? 4 : 1][DUAL ? 4 : 1];
  const f32x4 zero = {0.f, 0.f, 0.f, 0.f};
  #pragma unroll
  for (int m = 0; m < 4; ++m)
    #pragma unroll
    for (int n = 0; n < 4; ++n){
      acc1[m][n] = zero;
      if constexpr (DUAL) acc3[m][n] = zero;
    }

  const int KT = K >> 5;
  // prologue: stage kt=0
  GLOAD16(pa0, asBase + aW0);
  GLOAD16(pa1, asBase + aW1);
  float4 q1a = *(const float4*)(pb1);
  float4 q1b = *(const float4*)(pb1 + 4);
  float4 q1c = *(const float4*)(pb1 + 8);
  float4 q1d = *(const float4*)(pb1 + 12);
  float4 q3a, q3b, q3c, q3d;
  if constexpr (DUAL){
    q3a = *(const float4*)(pb3);
    q3b = *(const float4*)(pb3 + 4);
    q3c = *(const float4*)(pb3 + 8);
    q3d = *(const float4*)(pb3 + 12);
  }
  pa0 += 32; pa1 += 32; pb1 += 32; if constexpr (DUAL) pb3 += 32;
  int cur = 0;

  for (int kt = 0; kt < KT; ++kt){
    __syncthreads();                 // prev reads done; vmem (A[cur] + B regs) drained
    {
      bf16x8 u0, u1;
      u0[0]=(short)f2bf(q1a.x); u0[1]=(short)f2bf(q1a.y); u0[2]=(short)f2bf(q1a.z); u0[3]=(short)f2bf(q1a.w);
      u0[4]=(short)f2bf(q1b.x); u0[5]=(short)f2bf(q1b.y); u0[6]=(short)f2bf(q1b.z); u0[7]=(short)f2bf(q1b.w);
      u1[0]=(short)f2bf(q1c.x); u1[1]=(short)f2bf(q1c.y); u1[2]=(short)f2bf(q1c.z); u1[3]=(short)f2bf(q1c.w);
      u1[4]=(short)f2bf(q1d.x); u1[5]=(short)f2bf(q1d.y); u1[6]=(short)f2bf(q1d.z); u1[7]=(short)f2bf(q1d.w);
      *(bf16x8*)(&Bs1[bo0]) = u0;
      *(bf16x8*)(&Bs1[bo1]) = u1;
      if constexpr (DUAL){
        bf16x8 v0, v1;
        v0[0]=(short)f2bf(q3a.x); v0[1]=(short)f2bf(q3a.y); v0[2]=(short)f2bf(q3a.z); v0[3]=(short)f2bf(q3a.w);
        v0[4]=(short)f2bf(q3b.x); v0[5]=(short)f2bf(q3b.y); v0[6]=(short)f2bf(q3b.z); v0[7]=(short)f2bf(q3b.w);
        v1[0]=(short)f2bf(q3c.x); v1[1]=(short)f2bf(q3c.y); v1[2]=(short)f2bf(q3c.z); v1[3]=(short)f2bf(q3c.w);
        v1[4]=(short)f2bf(q3d.x); v1[5]=(short)f2bf(q3d.y); v1[6]=(short)f2bf(q3d.z); v1[7]=(short)f2bf(q3d.w);
        *(bf16x8*)(&Bs3[bo0]) = v0;
        *(bf16x8*)(&Bs3[bo1]) = v1;
      }
    }
    __syncthreads();                 // Bs + As[cur] visible
    if (kt + 1 < KT){                // issue-early: flies under the MFMA phase
      const int nxt = cur ^ 1;
      GLOAD16(pa0, asBase + nxt * bufStride + aW0);
      GLOAD16(pa1, asBase + nxt * bufStride + aW1);
      q1a = *(const float4*)(pb1);
      q1b = *(const float4*)(pb1 + 4);
      q1c = *(const float4*)(pb1 + 8);
      q1d = *(const float4*)(pb1 + 12);
      if constexpr (DUAL){
        q3a = *(const float4*)(pb3);
        q3b = *(const float4*)(pb3 + 4);
        q3c = *(const float4*)(pb3 + 8);
        q3d = *(const float4*)(pb3 + 12);
      }
      pa0 += 32; pa1 += 32; pb1 += 32; if constexpr (DUAL) pb3 += 32;
    }
    const unsigned short* aCur = asBase + cur * bufStride;
    bf16x8 af[4];
    #pragma unroll
    for (int m = 0; m < 4; ++m) af[m] = *(const bf16x8*)(aCur + aoff[m]);
    #pragma unroll
    for (int n = 0; n < 4; ++n){
      const bf16x8 b1f = *(const bf16x8*)(&Bs1[boff[n]]);
      #pragma unroll
      for (int m = 0; m < 4; ++m)
        acc1[m][n] = __builtin_amdgcn_mfma_f32_16x16x32_bf16(af[m], b1f, acc1[m][n], 0, 0, 0);
      if constexpr (DUAL){
        const bf16x8 b3f = *(const bf16x8*)(&Bs3[boff[n]]);
        #pragma unroll
        for (int m = 0; m < 4; ++m)
          acc3[m][n] = __builtin_amdgcn_mfma_f32_16x16x32_bf16(af[m], b3f, acc3[m][n], 0, 0, 0);
      }
    }
    cur ^= 1;
  }

  // ---- epilogue: C/D col = lane&15, row = (lane>>4)*4 + reg ----
  const int colBase = nt * 128 + wc * 64;
  #pragma unroll
  for (int m = 0; m < 4; ++m){
    #pragma unroll
    for (int r = 0; r < 4; ++r){
      const int grow = mt * 128 + wr * 64 + m * 16 + lq * 4 + r;
      if constexpr (MODE == 1){
        float* op = (float*)OutP + (size_t)grow * N + colBase;
        #pragma unroll
        for (int n = 0; n < 4; ++n) op[n * 16 + lr] = acc1[m][n][r];
      } else if constexpr (MODE == 0){
        unsigned short* op = (unsigned short*)OutP + (size_t)grow * N + colBase;
        #pragma unroll
        for (int n = 0; n < 4; ++n){
          const float g = acc1[m][n][r], u = acc3[m][n][r];
          op[n * 16 + lr] = f2bf(g / (1.f + __expf(-g)) * u);
        }
      } else {
        if (grow >= cntE) continue;
        const int orow = list[e * T_TOK + grow];    // slot
        unsigned short* op = (unsigned short*)OutP + (size_t)orow * N + colBase;
        if constexpr (MODE == 2){
          #pragma unroll
          for (int n = 0; n < 4; ++n){
            const float g = acc1[m][n][r], u = acc3[m][n][r];
            op[n * 16 + lr] = f2bf(g / (1.f + __expf(-g)) * u);
          }
        } else {
          #pragma unroll
          for (int n = 0; n < 4; ++n) op[n * 16 + lr] = f2bf(acc1[m][n][r]);
        }
      }
    }
  }
}

// ---------------- combine: out[t] += sum_k wslot[4t+k] * H2[4t+k] ----------------
__global__ void combine_kernel(const unsigned short* __restrict__ H2,
                               const float* __restrict__ wslot,
                               float* __restrict__ out){
  const int t = blockIdx.x;
  const int c = threadIdx.x * 8;
  float w[4];
  #pragma unroll
  for (int k = 0; k < 4; ++k) w[k] = wslot[t * 4 + k];
  float* o = out + (size_t)t * D_MODEL + c;
  float a[8];
  #pragma unroll
  for (int j = 0; j < 8; ++j) a[j] = o[j];
  #pragma unroll
  for (int k = 0; k < 4; ++k){
    const bf16x8 hv = *(const bf16x8*)(H2 + (size_t)(t * 4 + k) * D_MODEL + c);
    #pragma unroll
    for (int j = 0; j < 8; ++j) a[j] += w[k] * bf2f((unsigned short)hv[j]);
  }
  #pragma unroll
  for (int j = 0; j < 8; ++j) o[j] = a[j];
}

extern "C" void kernel_launch(void* const* d_in, const int* in_sizes, int n_in,
                              void* d_out, int out_size, void* d_ws, size_t ws_size,
                              hipStream_t stream)
{
  const float* x   = (const float*)d_in[0];
  const float* Wg  = (const float*)d_in[1];
  const float* W1  = (const float*)d_in[2];
  const float* W3  = (const float*)d_in[3];
  const float* W2  = (const float*)d_in[4];
  const float* Ws1 = (const float*)d_in[5];
  const float* Ws3 = (const float*)d_in[6];
  const float* Ws2 = (const float*)d_in[7];
  float* out = (float*)d_out;

  char* ws = (char*)d_ws;
  int*            cnt   = (int*)(ws);                       // 64 B
  int*            list  = (int*)(ws + 4096);                // 128 KiB
  float*          wslot = (float*)(ws + 4096 + 131072);     // 32 KiB
  unsigned short* xbf = (unsigned short*)(ws + ((size_t)1  << 20));  // 8.4 MB
  unsigned short* Hs  = (unsigned short*)(ws + ((size_t)10 << 20));  // 11.6 MB
  unsigned short* Hr  = (unsigned short*)(ws + ((size_t)22 << 20));  // 23.1 MB
  unsigned short* H2  = (unsigned short*)(ws + ((size_t)46 << 20));  // 33.6 MB

  hipMemsetAsync(cnt, 0, 4096, stream);
  cvt_bf16_kernel<<<(T_TOK * D_MODEL / 4) / 256, 256, 0, stream>>>(x, xbf, T_TOK * D_MODEL / 4);
  gate_kernel<<<T_TOK, 64, 0, stream>>>(x, Wg, cnt, list, wslot);

  // shared gate+up fused -> Hs  (M=2048, N=2816, K=2048)
  gemm3_kernel<0><<<16 * 22, 256, 0, stream>>>(xbf, Ws1, Ws3, Hs, nullptr, nullptr,
                                               SH_INTER, D_MODEL, 16, 22);
  // shared down -> out (fp32 stores initialize d_out)  (M=2048, N=2048, K=2816)
  gemm3_kernel<1><<<16 * 16, 256, 0, stream>>>(Hs, Ws2, nullptr, out, nullptr, nullptr,
                                               D_MODEL, SH_INTER, 16, 16);
  // routed gate+up fused -> Hr[slot]  (per-expert gather, N=1408, K=2048)
  gemm3_kernel<2><<<16 * 11 * 16, 256, 0, stream>>>(xbf, W1, W3, Hr, list, cnt,
                                                    N_INTER, D_MODEL, 16, 11);
  // routed down -> H2[slot]  (per-expert gather, N=2048, K=1408)
  gemm3_kernel<3><<<16 * 16 * 16, 256, 0, stream>>>(Hr, W2, nullptr, H2, list, cnt,
                                                    D_MODEL, N_INTER, 16, 16);
  // combine routed into out
  combine_kernel<<<T_TOK, 256, 0, stream>>>(H2, wslot, out);
}

// Round 4
// 670.845 us; speedup vs baseline: 1.3337x; 1.2381x over previous
//
#include <hip/hip_runtime.h>
#include <stdint.h>

// ---- problem constants ----
#define D_MODEL  2048
#define N_INTER  1408
#define SH_INTER 2816
#define T_TOK    2048
#define NSLOT    (T_TOK * 4)

typedef __attribute__((ext_vector_type(8))) short bf16x8;
typedef __attribute__((ext_vector_type(4))) float f32x4;

__device__ __forceinline__ unsigned short f2bf(float f){
  unsigned int b = __builtin_bit_cast(unsigned int, f);
  b = (b + 0x7FFFu + ((b >> 16) & 1u)) >> 16;   // RNE, finite inputs
  return (unsigned short)b;
}
__device__ __forceinline__ float bf2f(unsigned short h){
  unsigned int b = ((unsigned int)h) << 16;
  return __builtin_bit_cast(float, b);
}

// async global->LDS, 16B per lane; LDS dest = wave-uniform base + lane*16
#define GLOAD16(gp, lp) __builtin_amdgcn_global_load_lds( \
    (const __attribute__((address_space(1))) unsigned int*)(gp), \
    (__attribute__((address_space(3))) unsigned int*)(lp), 16, 0, 0)

// ---------------- fp32 -> bf16 streaming convert (grid-stride) ----------------
__global__ void cvt_bf16_kernel(const float* __restrict__ x,
                                unsigned short* __restrict__ o, int n4){
  const int stride = gridDim.x * blockDim.x;
  for (int i = blockIdx.x * blockDim.x + threadIdx.x; i < n4; i += stride){
    const float4 v = ((const float4*)x)[i];
    ushort4 u; u.x = f2bf(v.x); u.y = f2bf(v.y); u.z = f2bf(v.z); u.w = f2bf(v.w);
    ((ushort4*)o)[i] = u;
  }
}

// ---------------- gate: softmax + group-limited top-k ----------------
__global__ void gate_kernel(const float* __restrict__ x, const float* __restrict__ Wg,
                            int* __restrict__ cnt, int* __restrict__ list,
                            float* __restrict__ wslot){
  const int t = blockIdx.x;
  const int l = threadIdx.x;
  const int e = l & 15, q = l >> 4;
  const float* xr = x + (size_t)t * D_MODEL + q * 512;
  const float* wr = Wg + (size_t)e * D_MODEL + q * 512;
  float p = 0.f;
  #pragma unroll 4
  for (int i = 0; i < 512; i += 4){
    float4 xv = *(const float4*)(xr + i);
    float4 wv = *(const float4*)(wr + i);
    p += xv.x*wv.x + xv.y*wv.y + xv.z*wv.z + xv.w*wv.w;
  }
  p += __shfl_xor(p, 16);
  p += __shfl_xor(p, 32);
  float mx = p;
  for (int d = 1; d < 16; d <<= 1) mx = fmaxf(mx, __shfl_xor(mx, d));
  float ex = __expf(p - mx);
  float sum = ex;
  for (int d = 1; d < 16; d <<= 1) sum += __shfl_xor(sum, d);
  const float sc = ex / sum;
  float gm = fmaxf(sc, __shfl_xor(sc, 1));
  gm = fmaxf(gm, __shfl_xor(gm, 2));
  const float g0 = __shfl(gm, 0), g1 = __shfl(gm, 4),
              g2 = __shfl(gm, 8), g3 = __shfl(gm, 12);
  const int grp = e >> 2;
  const float gs[4] = {g0, g1, g2, g3};
  int grank = 0;
  #pragma unroll
  for (int j = 0; j < 4; ++j)
    if (gs[j] > gm || (gs[j] == gm && j < grp)) grank++;
  const float msc = (grank < 2) ? sc : -INFINITY;
  int erank = 0;
  #pragma unroll
  for (int j = 0; j < 16; ++j){
    const float oj = __shfl(msc, j);
    if (oj > msc || (oj == msc && j < e)) erank++;
  }
  if (q == 0 && erank < 4 && msc > -INFINITY){
    const int pos = atomicAdd(&cnt[e], 1);
    const int slot = (t << 2) | erank;
    list[e * T_TOK + pos] = slot;
    wslot[slot] = sc;            // ROUTE_SCALE = 1
  }
}

// ---- m97-structure GEMM: BM=128 BN=128 BK=32, 4 waves (2x2 of 64x64) ----
// A bf16 [*][K], B bf16 [E?][N][K]; both staged via double-buffered
// global_load_lds (pre-swizzled source, XOR read). One barrier per K-step.
// MODE 0: linear A, bf16 out          MODE 1: linear A, fp32 out
// MODE 2: gather A by token (entry>>2), bf16 out at slot
// MODE 3: gather A by slot (entry),     bf16 out at slot
template<int MODE>
__global__ __launch_bounds__(256, 2)
void gemm4_kernel(const unsigned short* __restrict__ A,
                  const unsigned short* __restrict__ B,
                  void* __restrict__ OutP,
                  const int* __restrict__ list,
                  const int* __restrict__ cnt,
                  int N, int K, int MT, int NT)
{
  constexpr bool GATHER = (MODE >= 2);
  __shared__ unsigned short As[2 * 128 * 32];
  __shared__ unsigned short Bs[2 * 128 * 32];

  // bijective XCD-chunked swizzle (all grids % 8 == 0)
  const int per = gridDim.x >> 3;
  const int gsw = (blockIdx.x & 7) * per + (blockIdx.x >> 3);
  const int mt   = gsw % MT;
  const int rest = gsw / MT;
  const int nt = GATHER ? (rest % NT) : rest;
  const int e  = GATHER ? (rest / NT) : 0;

  const int cntE = GATHER ? cnt[e] : (MT * 128);
  if (mt * 128 >= cntE) return;

  const int tid = threadIdx.x, wid = tid >> 6, lane = tid & 63;

  // wave w stages tile rows [32w, 32w+32) as 2 chunks of 16 rows;
  // lane -> row += lane>>2, phys 16B-slot = lane&3; src slot = phys ^ ((row>>1)&3)
  const int rt0 = 32 * wid + (lane >> 2), rt1 = rt0 + 16;
  const int sx0 = ((lane & 3) ^ ((rt0 >> 1) & 3)) << 3;   // shorts
  const int sx1 = ((lane & 3) ^ ((rt1 >> 1) & 3)) << 3;

  int ar0, ar1;
  if constexpr (GATHER){
    const int lim = cntE - 1;
    int p0 = mt * 128 + rt0; p0 = p0 < lim ? p0 : lim;
    int p1 = mt * 128 + rt1; p1 = p1 < lim ? p1 : lim;
    const int e0 = list[e * T_TOK + p0], e1 = list[e * T_TOK + p1];
    ar0 = (MODE == 2) ? (e0 >> 2) : e0;
    ar1 = (MODE == 2) ? (e1 >> 2) : e1;
  } else { ar0 = mt * 128 + rt0; ar1 = mt * 128 + rt1; }

  const unsigned short* pa0 = A + (size_t)ar0 * K + sx0;
  const unsigned short* pa1 = A + (size_t)ar1 * K + sx1;
  const size_t Boff = GATHER ? (size_t)e * N * K : 0;
  const unsigned short* pb0 = B + Boff + (size_t)(nt * 128 + rt0) * K + sx0;
  const unsigned short* pb1 = B + Boff + (size_t)(nt * 128 + rt1) * K + sx1;

  const int aW0 = (32 * wid) * 32, aW1 = (32 * wid + 16) * 32;  // shorts
  const int bufStride = 128 * 32;

  // fragment read offsets (XOR-swizzled)
  const int wr = wid >> 1, wc = wid & 1, lr = lane & 15, lq = lane >> 4;
  const int fx = ((lq ^ ((lr >> 1) & 3)) << 3);
  int aoff[4], boff[4];
  #pragma unroll
  for (int m = 0; m < 4; ++m) aoff[m] = (wr * 64 + m * 16 + lr) * 32 + fx;
  #pragma unroll
  for (int n = 0; n < 4; ++n) boff[n] = (wc * 64 + n * 16 + lr) * 32 + fx;

  f32x4 acc[4][4];
  const f32x4 zero = {0.f, 0.f, 0.f, 0.f};
  #pragma unroll
  for (int m = 0; m < 4; ++m)
    #pragma unroll
    for (int n = 0; n < 4; ++n) acc[m][n] = zero;

  const int KT = K >> 5;
  // prologue: stage kt=0 into buffer 0
  GLOAD16(pa0, As + aW0);
  GLOAD16(pa1, As + aW1);
  GLOAD16(pb0, Bs + aW0);
  GLOAD16(pb1, Bs + aW1);
  pa0 += 32; pa1 += 32; pb0 += 32; pb1 += 32;
  int cur = 0;

  for (int kt = 0; kt < KT; ++kt){
    __syncthreads();                 // drains vmcnt: buf[cur] staged; prev reads done
    if (kt + 1 < KT){                // prefetch next tile; flies under MFMA phase
      const int nx = cur ^ 1;
      GLOAD16(pa0, As + nx * bufStride + aW0);
      GLOAD16(pa1, As + nx * bufStride + aW1);
      GLOAD16(pb0, Bs + nx * bufStride + aW0);
      GLOAD16(pb1, Bs + nx * bufStride + aW1);
      pa0 += 32; pa1 += 32; pb0 += 32; pb1 += 32;
    }
    const unsigned short* aC = As + cur * bufStride;
    const unsigned short* bC = Bs + cur * bufStride;
    bf16x8 af[4];
    #pragma unroll
    for (int m = 0; m < 4; ++m) af[m] = *(const bf16x8*)(aC + aoff[m]);
    #pragma unroll
    for (int n = 0; n < 4; ++n){
      const bf16x8 bfr = *(const bf16x8*)(bC + boff[n]);
      #pragma unroll
      for (int m = 0; m < 4; ++m)
        acc[m][n] = __builtin_amdgcn_mfma_f32_16x16x32_bf16(af[m], bfr, acc[m][n], 0, 0, 0);
    }
    cur ^= 1;
  }

  // ---- epilogue: C/D col = lane&15, row = (lane>>4)*4 + reg ----
  const int colBase = nt * 128 + wc * 64;
  #pragma unroll
  for (int m = 0; m < 4; ++m){
    #pragma unroll
    for (int r = 0; r < 4; ++r){
      const int grow = mt * 128 + wr * 64 + m * 16 + lq * 4 + r;
      if constexpr (MODE == 1){
        float* op = (float*)OutP + (size_t)grow * N + colBase;
        #pragma unroll
        for (int n = 0; n < 4; ++n) op[n * 16 + lr] = acc[m][n][r];
      } else if constexpr (MODE == 0){
        unsigned short* op = (unsigned short*)OutP + (size_t)grow * N + colBase;
        #pragma unroll
        for (int n = 0; n < 4; ++n) op[n * 16 + lr] = f2bf(acc[m][n][r]);
      } else {
        if (grow >= cntE) continue;
        const int orow = list[e * T_TOK + grow];    // slot
        unsigned short* op = (unsigned short*)OutP + (size_t)orow * N + colBase;
        #pragma unroll
        for (int n = 0; n < 4; ++n) op[n * 16 + lr] = f2bf(acc[m][n][r]);
      }
    }
  }
}

// ---------------- SwiGLU in place: G = silu(G) * U (bf16) ----------------
__global__ void swiglu_kernel(unsigned short* __restrict__ G,
                              const unsigned short* __restrict__ U, int n8){
  const int stride = gridDim.x * blockDim.x;
  for (int i = blockIdx.x * blockDim.x + threadIdx.x; i < n8; i += stride){
    const bf16x8 g = ((const bf16x8*)G)[i];
    const bf16x8 u = ((const bf16x8*)U)[i];
    bf16x8 h;
    #pragma unroll
    for (int j = 0; j < 8; ++j){
      const float gv = bf2f((unsigned short)g[j]);
      const float uv = bf2f((unsigned short)u[j]);
      h[j] = (short)f2bf(gv / (1.f + __expf(-gv)) * uv);
    }
    ((bf16x8*)G)[i] = h;
  }
}

// ---------------- combine: out[t] += sum_k wslot[4t+k] * H2[4t+k] ----------------
__global__ void combine_kernel(const unsigned short* __restrict__ H2,
                               const float* __restrict__ wslot,
                               float* __restrict__ out){
  const int t = blockIdx.x;
  const int c = threadIdx.x * 8;
  float w[4];
  #pragma unroll
  for (int k = 0; k < 4; ++k) w[k] = wslot[t * 4 + k];
  float* o = out + (size_t)t * D_MODEL + c;
  float a[8];
  #pragma unroll
  for (int j = 0; j < 8; ++j) a[j] = o[j];
  #pragma unroll
  for (int k = 0; k < 4; ++k){
    const bf16x8 hv = *(const bf16x8*)(H2 + (size_t)(t * 4 + k) * D_MODEL + c);
    #pragma unroll
    for (int j = 0; j < 8; ++j) a[j] += w[k] * bf2f((unsigned short)hv[j]);
  }
  #pragma unroll
  for (int j = 0; j < 8; ++j) o[j] = a[j];
}

extern "C" void kernel_launch(void* const* d_in, const int* in_sizes, int n_in,
                              void* d_out, int out_size, void* d_ws, size_t ws_size,
                              hipStream_t stream)
{
  const float* x   = (const float*)d_in[0];
  const float* Wg  = (const float*)d_in[1];
  const float* W1  = (const float*)d_in[2];
  const float* W3  = (const float*)d_in[3];
  const float* W2  = (const float*)d_in[4];
  const float* Ws1 = (const float*)d_in[5];
  const float* Ws3 = (const float*)d_in[6];
  const float* Ws2 = (const float*)d_in[7];
  float* out = (float*)d_out;

  // ---- phase-reused workspace (max touched address: 145 MiB) ----
  char* ws = (char*)d_ws;
  int*   cnt   = (int*)(ws);                     // 64 B
  int*   list  = (int*)(ws + 4096);              // 128 KiB
  float* wslot = (float*)(ws + 4096 + 131072);   // 32 KiB
  unsigned short* xbf  = (unsigned short*)(ws + ((size_t)1   << 20)); // 8 MiB  (dead before H2)
  unsigned short* H2   = (unsigned short*)(ws + ((size_t)1   << 20)); // 32 MiB (late)
  unsigned short* Ubuf = (unsigned short*)(ws + ((size_t)10  << 20)); // <=22 MiB (Us/Ur; dead before H2)
  unsigned short* Wb   = (unsigned short*)(ws + ((size_t)34  << 20)); // <=88 MiB (current bf16 weight)
  unsigned short* Gbuf = (unsigned short*)(ws + ((size_t)123 << 20)); // <=22 MiB (Gs/Gr -> H in place)
  unsigned short* Wb2  = Wb + (size_t)SH_INTER * D_MODEL;             // second shared weight slot

  hipMemsetAsync(cnt, 0, 4096, stream);
  cvt_bf16_kernel<<<2048, 256, 0, stream>>>(x, xbf, T_TOK * D_MODEL / 4);
  gate_kernel<<<T_TOK, 64, 0, stream>>>(x, Wg, cnt, list, wslot);

  // ---- shared expert ----
  cvt_bf16_kernel<<<4096, 256, 0, stream>>>(Ws1, Wb,  SH_INTER * D_MODEL / 4);
  cvt_bf16_kernel<<<4096, 256, 0, stream>>>(Ws3, Wb2, SH_INTER * D_MODEL / 4);
  gemm4_kernel<0><<<16 * 22, 256, 0, stream>>>(xbf, Wb,  Gbuf, nullptr, nullptr,
                                               SH_INTER, D_MODEL, 16, 22);
  gemm4_kernel<0><<<16 * 22, 256, 0, stream>>>(xbf, Wb2, Ubuf, nullptr, nullptr,
                                               SH_INTER, D_MODEL, 16, 22);
  swiglu_kernel<<<2048, 256, 0, stream>>>(Gbuf, Ubuf, T_TOK * SH_INTER / 8);
  cvt_bf16_kernel<<<4096, 256, 0, stream>>>(Ws2, Wb, D_MODEL * SH_INTER / 4);
  gemm4_kernel<1><<<16 * 16, 256, 0, stream>>>(Gbuf, Wb, out, nullptr, nullptr,
                                               D_MODEL, SH_INTER, 16, 16);   // init out

  // ---- routed experts ----
  cvt_bf16_kernel<<<8192, 256, 0, stream>>>(W1, Wb, 16 * N_INTER * D_MODEL / 4);
  gemm4_kernel<2><<<16 * 11 * 16, 256, 0, stream>>>(xbf, Wb, Gbuf, list, cnt,
                                                    N_INTER, D_MODEL, 16, 11);
  cvt_bf16_kernel<<<8192, 256, 0, stream>>>(W3, Wb, 16 * N_INTER * D_MODEL / 4);
  gemm4_kernel<2><<<16 * 11 * 16, 256, 0, stream>>>(xbf, Wb, Ubuf, list, cnt,
                                                    N_INTER, D_MODEL, 16, 11);
  swiglu_kernel<<<2048, 256, 0, stream>>>(Gbuf, Ubuf, NSLOT * N_INTER / 8);
  cvt_bf16_kernel<<<8192, 256, 0, stream>>>(W2, Wb, 16 * D_MODEL * N_INTER / 4);
  gemm4_kernel<3><<<16 * 16 * 16, 256, 0, stream>>>(Gbuf, Wb, H2, list, cnt,
                                                    D_MODEL, N_INTER, 16, 16);
  combine_kernel<<<T_TOK, 256, 0, stream>>>(H2, wslot, out);
}